// Round 8
// baseline (719.940 us; speedup 1.0000x reference)
//
#include <hip/hip_runtime.h>

// Problem constants: B=8, N=2048, D=768
#define NN 2048
#define DD 768
#define BN 16384              // rows per tensor
#define ROWS 32768            // total rows (H then doc_sents_h)
#define GROUPS 16             // ROWS / NN (independent (tensor,batch) groups)
#define IPG 128               // items per group (scores and edges each)
#define SITEMS 2048           // scores items, 16 rows each
#define TOTAL 4096            // total items = blocks

typedef float f4 __attribute__((ext_vector_type(4)));

// Pop index -> work item. Schedule: [S g0]x128, then for q=0..14:
// [S g(q+1)]x128, [E gq]x128, finally [E g15]x128.
// Guarantees all scores items of group g are popped before any edges item of
// group g -> spinning consumers always have their producers running-or-done
// (deadlock-free regardless of dispatch order or occupancy).
__device__ __forceinline__ void map_pop(int p, int& kind, int& idx) {
    if (p < IPG) { kind = 0; idx = p; return; }
    p -= IPG;
    if (p < 15 * 2 * IPG) {
        const int q = p / (2 * IPG), r = p % (2 * IPG);
        if (r < IPG) { kind = 0; idx = (q + 1) * IPG + r; }
        else         { kind = 1; idx = q * IPG + (r - IPG); }
        return;
    }
    p -= 15 * 2 * IPG;
    kind = 1; idx = 15 * IPG + p;
}

// ctr[0] = pop counter; ctr[1+g] = scores items completed for group g.
__global__ __launch_bounds__(256) void fused_wq_kernel(
        const float* __restrict__ H,
        const float* __restrict__ Dh,
        const float* __restrict__ W,
        const float* __restrict__ bias,
        float* __restrict__ ssrc,
        float* __restrict__ sdst,
        int* __restrict__ ctr,
        float* __restrict__ out) {
    __shared__ int sh[2];
    if (threadIdx.x == 0) {
        const int p = __hip_atomic_fetch_add(&ctr[0], 1, __ATOMIC_RELAXED,
                                             __HIP_MEMORY_SCOPE_AGENT);
        int kind, idx;
        map_pop(p, kind, idx);
        sh[0] = kind; sh[1] = idx;
    }
    __syncthreads();
    const int kind = sh[0], idx = sh[1];

    if (kind == 0) {
        // ---- scores item: rows [idx*16, idx*16+16), one row per wave x4 ----
        const int wave = threadIdx.x >> 6;
        const int lane = threadIdx.x & 63;
        const f4* wa4 = reinterpret_cast<const f4*>(W);
        const f4* wb4 = reinterpret_cast<const f4*>(W + DD);
        f4 wa[3], wb[3];
#pragma unroll
        for (int w = 0; w < 3; ++w) {
            wa[w] = wa4[lane + 64 * w];
            wb[w] = wb4[lane + 64 * w];
        }
        const float bb = bias[0];
#pragma unroll
        for (int i = 0; i < 4; ++i) {
            const int row = idx * 16 + i * 4 + wave;
            const float* x = (row < BN) ? (H + (size_t)row * DD)
                                        : (Dh + (size_t)(row - BN) * DD);
            const f4* x4 = reinterpret_cast<const f4*>(x);
            float sa = 0.0f, sb = 0.0f;
#pragma unroll
            for (int w = 0; w < 3; ++w) {
                const f4 xv = x4[lane + 64 * w];
                sa += xv.x * wa[w].x + xv.y * wa[w].y + xv.z * wa[w].z + xv.w * wa[w].w;
                sb += xv.x * wb[w].x + xv.y * wb[w].y + xv.z * wb[w].z + xv.w * wb[w].w;
            }
#pragma unroll
            for (int off = 32; off > 0; off >>= 1) {
                sa += __shfl_down(sa, off, 64);
                sb += __shfl_down(sb, off, 64);
            }
            if (lane == 0) {
                ssrc[row] = sa + bb;
                sdst[row] = sb;
            }
        }
        // All waves' stores drained by the barrier's vmcnt(0); then publish.
        __syncthreads();
        if (threadIdx.x == 0) {
            __threadfence();   // agent-scope: make ssrc/sdst visible cross-XCD
            __hip_atomic_fetch_add(&ctr[1 + idx / IPG], 1, __ATOMIC_RELEASE,
                                   __HIP_MEMORY_SCOPE_AGENT);
        }
    } else {
        // ---- edges item: output rows [idx*16, idx*16+16) ----
        const int g = idx / IPG;
        if (threadIdx.x == 0) {
            while (__hip_atomic_load(&ctr[1 + g], __ATOMIC_ACQUIRE,
                                     __HIP_MEMORY_SCOPE_AGENT) < IPG)
                __builtin_amdgcn_s_sleep(1);
            __threadfence();   // invalidate caches before reading scores
        }
        __syncthreads();

        const int row0  = idx * 16;
        const int group = g * NN;
        const f4* sd4 = reinterpret_cast<const f4*>(sdst + group);
        const f4 d0 = sd4[threadIdx.x];
        const f4 d1 = sd4[threadIdx.x + 256];

        float s[16];
#pragma unroll
        for (int r = 0; r < 16; ++r) s[r] = ssrc[row0 + r];

        f4* o4 = reinterpret_cast<f4*>(out + (size_t)row0 * NN);
#pragma unroll
        for (int r = 0; r < 16; ++r) {
            f4 a, b;
            a.x = fmaxf(s[r] + d0.x, 0.0f);
            a.y = fmaxf(s[r] + d0.y, 0.0f);
            a.z = fmaxf(s[r] + d0.z, 0.0f);
            a.w = fmaxf(s[r] + d0.w, 0.0f);
            b.x = fmaxf(s[r] + d1.x, 0.0f);
            b.y = fmaxf(s[r] + d1.y, 0.0f);
            b.z = fmaxf(s[r] + d1.z, 0.0f);
            b.w = fmaxf(s[r] + d1.w, 0.0f);
            __builtin_nontemporal_store(a, &o4[(size_t)r * 512 + threadIdx.x]);
            __builtin_nontemporal_store(b, &o4[(size_t)r * 512 + threadIdx.x + 256]);
        }
    }
}

extern "C" void kernel_launch(void* const* d_in, const int* in_sizes, int n_in,
                              void* d_out, int out_size, void* d_ws, size_t ws_size,
                              hipStream_t stream) {
    const float* H    = (const float*)d_in[0];
    const float* Dh   = (const float*)d_in[1];
    const float* W    = (const float*)d_in[2];
    const float* bias = (const float*)d_in[3];
    float* out  = (float*)d_out;

    float* ssrc = (float*)d_ws;                    // ROWS floats
    float* sdst = ssrc + ROWS;                     // ROWS floats
    int*   ctr  = (int*)(sdst + ROWS);             // 1 + GROUPS ints

    hipMemsetAsync(ctr, 0, (1 + GROUPS) * sizeof(int), stream);
    fused_wq_kernel<<<TOTAL, 256, 0, stream>>>(H, Dh, W, bias,
                                               ssrc, sdst, ctr, out);
}

// Round 9
// 67.749 us; speedup vs baseline: 10.6266x; 10.6266x over previous
//
#include <hip/hip_runtime.h>

// Problem constants (from reference): B=8, N=2048, D=768
#define BB 8
#define NN 2048
#define DD 768
#define BN (BB * NN)          // 16384 rows per tensor
#define ROWS (2 * BN)         // 32768 rows total (H then doc_sents_h)
#define RPB 32                // rows per block in edges kernel

// clang-native 16B vector (HIP's float4 is a struct the NT builtins reject)
typedef float f4 __attribute__((ext_vector_type(4)));

// Kernel 1: per-row dual dot product.
// One wave (64 lanes) per row. 768 floats = 192 f4 per row = 3 f4/lane.
__global__ __launch_bounds__(256) void scores_kernel(
        const float* __restrict__ H,
        const float* __restrict__ Dh,
        const float* __restrict__ W,
        const float* __restrict__ bias,
        float* __restrict__ ssrc,
        float* __restrict__ sdst) {
    const int wave = threadIdx.x >> 6;              // 0..3
    const int lane = threadIdx.x & 63;
    const int row  = blockIdx.x * 4 + wave;         // 0..ROWS-1

    const float* x = (row < BN) ? (H + (size_t)row * DD)
                                : (Dh + (size_t)(row - BN) * DD);
    const f4* x4  = reinterpret_cast<const f4*>(x);
    const f4* wa4 = reinterpret_cast<const f4*>(W);
    const f4* wb4 = reinterpret_cast<const f4*>(W + DD);

    float sa = 0.0f, sb = 0.0f;
#pragma unroll
    for (int w = 0; w < 3; ++w) {
        const int idx = lane + w * 64;              // < 192
        const f4 xv = x4[idx];                      // regular (caching) load
        const f4 av = wa4[idx];
        const f4 bv = wb4[idx];
        sa += xv.x * av.x + xv.y * av.y + xv.z * av.z + xv.w * av.w;
        sb += xv.x * bv.x + xv.y * bv.y + xv.z * bv.z + xv.w * bv.w;
    }
    // wave64 shuffle reduction
#pragma unroll
    for (int off = 32; off > 0; off >>= 1) {
        sa += __shfl_down(sa, off, 64);
        sb += __shfl_down(sb, off, 64);
    }
    if (lane == 0) {
        ssrc[row] = sa + bias[0];                   // fold bias into src score
        sdst[row] = sb;
    }
}

// Kernel 2: out[row, j] = relu(ssrc[row] + sdst[group + j]) for j in [0, N)
// 32 rows per block (same batch group). Each thread holds the two f4 sdst
// fragments in registers, then issues 64 nontemporal f4 stores back-to-back.
__global__ __launch_bounds__(256) void edges_kernel(
        const float* __restrict__ ssrc,
        const float* __restrict__ sdst,
        float* __restrict__ out) {
    const int row0  = blockIdx.x * RPB;             // multiple of 32; NN%32==0
    const int group = (row0 / NN) * NN;
    const f4* sd4 = reinterpret_cast<const f4*>(sdst + group);
    const f4 d0 = sd4[threadIdx.x];
    const f4 d1 = sd4[threadIdx.x + 256];

    f4* o4 = reinterpret_cast<f4*>(out + (size_t)row0 * NN);
#pragma unroll
    for (int r = 0; r < RPB; ++r) {
        const float s = ssrc[row0 + r];
        f4 a, b;
        a.x = fmaxf(s + d0.x, 0.0f);
        a.y = fmaxf(s + d0.y, 0.0f);
        a.z = fmaxf(s + d0.z, 0.0f);
        a.w = fmaxf(s + d0.w, 0.0f);
        b.x = fmaxf(s + d1.x, 0.0f);
        b.y = fmaxf(s + d1.y, 0.0f);
        b.z = fmaxf(s + d1.z, 0.0f);
        b.w = fmaxf(s + d1.w, 0.0f);
        __builtin_nontemporal_store(a, &o4[(size_t)r * 512 + threadIdx.x]);
        __builtin_nontemporal_store(b, &o4[(size_t)r * 512 + threadIdx.x + 256]);
    }
}

extern "C" void kernel_launch(void* const* d_in, const int* in_sizes, int n_in,
                              void* d_out, int out_size, void* d_ws, size_t ws_size,
                              hipStream_t stream) {
    const float* H    = (const float*)d_in[0];
    const float* Dh   = (const float*)d_in[1];
    const float* W    = (const float*)d_in[2];
    const float* bias = (const float*)d_in[3];
    float* out  = (float*)d_out;

    float* ssrc = (float*)d_ws;          // ROWS floats
    float* sdst = ssrc + ROWS;           // ROWS floats  (total 256 KB scratch)

    scores_kernel<<<ROWS / 4, 256, 0, stream>>>(H, Dh, W, bias, ssrc, sdst);
    edges_kernel<<<ROWS / RPB, 256, 0, stream>>>(ssrc, sdst, out);
}